// Round 1
// baseline (127.886 us; speedup 1.0000x reference)
//
#include <hip/hip_runtime.h>
#include <hip/hip_bf16.h>

// Problem constants (from reference): N=2,000,000 nodes, IN=64, OUT=128, G=16384.
// x: [N,64] f32, segment_ids: [N] int32 (sorted), weight: [128,64] f32, bias: [128] f32.
// out: [G,128] f32.

#define IN_CH 64
#define OUT_CH 128

// Kernel 1: starts[g] = lower_bound(ids, n, g) for g in [0, G].  counts[g] = starts[g+1]-starts[g].
__global__ void seg_starts_kernel(const int* __restrict__ ids, int n, int G,
                                  int* __restrict__ starts) {
    int g = blockIdx.x * blockDim.x + threadIdx.x;
    if (g > G) return;
    int lo = 0, hi = n;
    while (lo < hi) {
        int mid = (lo + hi) >> 1;
        if (ids[mid] < g) lo = mid + 1; else hi = mid;
    }
    starts[g] = lo;
}

// Kernel 2: one wave per graph. Pool (mean over contiguous row range) + linear, fused.
__global__ __launch_bounds__(256) void pool_linear_kernel(
        const float* __restrict__ x, const float* __restrict__ W,
        const float* __restrict__ bias, const int* __restrict__ starts,
        float* __restrict__ out, int G) {
    // W transposed into LDS: w_lds[c*129 + o] = W[o*64 + c].  Stride 129 -> bank (c+o)%32.
    __shared__ float w_lds[IN_CH * 129];
    __shared__ float mean_s[4][IN_CH];

    const int t = threadIdx.x;
    // Cooperative W load (coalesced global reads; padded LDS writes conflict-free).
    for (int i = t; i < OUT_CH * IN_CH; i += 256) {
        int o = i >> 6;       // 0..127
        int c = i & 63;       // 0..63
        w_lds[c * 129 + o] = W[i];
    }

    const int wv = t >> 6;         // wave in block: 0..3
    const int l  = t & 63;         // lane
    const int g  = blockIdx.x * 4 + wv;

    const int rs = l >> 4;             // row stream 0..3
    const int cq = (l & 15) << 2;      // channel quad base: 0,4,...,60

    float4 acc = make_float4(0.f, 0.f, 0.f, 0.f);
    int s0 = 0, s1 = 0;
    if (g < G) { s0 = starts[g]; s1 = starts[g + 1]; }

    // Main loop: wave reads 4 rows (1 KiB contiguous) per iteration.
    int r = s0;
    for (; r + 4 <= s1; r += 4) {
        const float4 v = *reinterpret_cast<const float4*>(
            x + (size_t)(r + rs) * IN_CH + cq);
        acc.x += v.x; acc.y += v.y; acc.z += v.z; acc.w += v.w;
    }
    // Tail: 0..3 remaining rows.
    if (r + rs < s1) {
        const float4 v = *reinterpret_cast<const float4*>(
            x + (size_t)(r + rs) * IN_CH + cq);
        acc.x += v.x; acc.y += v.y; acc.z += v.z; acc.w += v.w;
    }

    // Reduce the 4 row streams: lanes l, l^16, l^32 hold the same channel slice.
    acc.x += __shfl_xor(acc.x, 16); acc.y += __shfl_xor(acc.y, 16);
    acc.z += __shfl_xor(acc.z, 16); acc.w += __shfl_xor(acc.w, 16);
    acc.x += __shfl_xor(acc.x, 32); acc.y += __shfl_xor(acc.y, 32);
    acc.z += __shfl_xor(acc.z, 32); acc.w += __shfl_xor(acc.w, 32);

    if (g < G && l < 16) {
        const float cnt = (float)(s1 - s0);
        mean_s[wv][cq + 0] = acc.x / cnt;
        mean_s[wv][cq + 1] = acc.y / cnt;
        mean_s[wv][cq + 2] = acc.z / cnt;
        mean_s[wv][cq + 3] = acc.w / cnt;
    }

    __syncthreads();   // covers W staging + per-wave mean_s visibility

    if (g < G) {
        float o0 = bias[l];
        float o1 = bias[l + 64];
        #pragma unroll
        for (int c = 0; c < IN_CH; ++c) {
            const float m = mean_s[wv][c];          // LDS broadcast
            o0 = fmaf(w_lds[c * 129 + l],      m, o0);
            o1 = fmaf(w_lds[c * 129 + l + 64], m, o1);
        }
        out[(size_t)g * OUT_CH + l]      = o0;
        out[(size_t)g * OUT_CH + l + 64] = o1;
    }
}

extern "C" void kernel_launch(void* const* d_in, const int* in_sizes, int n_in,
                              void* d_out, int out_size, void* d_ws, size_t ws_size,
                              hipStream_t stream) {
    const float* x    = (const float*)d_in[0];
    const int*   ids  = (const int*)d_in[1];
    const float* W    = (const float*)d_in[2];
    const float* bias = (const float*)d_in[3];
    float* out = (float*)d_out;

    const int N = in_sizes[1];             // 2,000,000
    const int G = out_size / OUT_CH;       // 16384

    int* starts = (int*)d_ws;              // (G+1) ints

    {
        const int total = G + 1;
        const int block = 256;
        seg_starts_kernel<<<(total + block - 1) / block, block, 0, stream>>>(
            ids, N, G, starts);
    }
    {
        const int blocks = (G + 3) / 4;    // 4 graphs (waves) per block
        pool_linear_kernel<<<blocks, 256, 0, stream>>>(x, W, bias, starts, out, G);
    }
}

// Round 2
// 111.812 us; speedup vs baseline: 1.1438x; 1.1438x over previous
//
#include <hip/hip_runtime.h>
#include <hip/hip_bf16.h>

// Problem: segment-mean over N=2,000,000 sorted nodes -> G=16384 graphs, then linear.
// x: [N,64] f32, segment_ids: [N] int32 (sorted), weight: [128,64] f32, bias: [128] f32.
// out: [G,128] f32.  Purely HBM-bound: ~520 MB read + 8 MB write -> ~84 us floor.

#define IN_CH 64
#define OUT_CH 128
#define WPB 8               // waves (= graphs) per block
#define BLOCK (WPB * 64)    // 512 threads

// Kernel 1: boundary scatter over the sorted id array.
// starts[g] = first i with ids[i] >= g, for g in [0, G]; starts[G] = n.
// Thread i writes starts[g] = i for all g in (ids[i-1], ids[i]]  (prev = -1 at i=0).
__global__ void seg_starts_kernel(const int* __restrict__ ids, int n, int G,
                                  int* __restrict__ starts) {
    int i = blockIdx.x * blockDim.x + threadIdx.x;
    if (i >= n) return;
    const int cur  = ids[i];
    const int prev = (i == 0) ? -1 : ids[i - 1];   // overlapping read, L1/L2-cached
    for (int g = prev + 1; g <= cur; ++g) starts[g] = i;
    if (i == n - 1) {
        for (int g = cur + 1; g <= G; ++g) starts[g] = n;
    }
}

// Kernel 2: one wave per graph; 8 graphs per 512-thread block sharing one W tile.
// LDS = 64*129*4 = 33 KB -> 4 blocks/CU -> 32 waves/CU (max occupancy).
__global__ __launch_bounds__(BLOCK) void pool_linear_kernel(
        const float* __restrict__ x, const float* __restrict__ W,
        const float* __restrict__ bias, const int* __restrict__ starts,
        float* __restrict__ out, int G) {
    // W transposed: w_lds[c*129 + o] = W[o][c]. Stride 129 keeps both the
    // cooperative writes (64 lanes, same o, c=lane -> bank lane%32, 2-way free)
    // and the epilogue reads (consecutive lanes -> consecutive addr) conflict-free.
    __shared__ float w_lds[IN_CH * 129];

    const int t = threadIdx.x;
    for (int i = t; i < OUT_CH * IN_CH; i += BLOCK) {
        const int o = i >> 6;     // 0..127
        const int c = i & 63;     // 0..63
        w_lds[c * 129 + o] = W[i];
    }
    __syncthreads();              // only barrier in the kernel

    const int wv = t >> 6;        // wave in block 0..7
    const int l  = t & 63;
    const int g  = blockIdx.x * WPB + wv;
    if (g >= G) return;

    const int rs = l >> 4;              // row stream 0..3
    const int cq = (l & 15) << 2;       // channel quad base

    const int s0 = starts[g];
    const int s1 = starts[g + 1];

    // Main loop: 8 rows / iter (two independent 1 KiB wave-loads in flight).
    float4 a0 = make_float4(0.f, 0.f, 0.f, 0.f);
    float4 a1 = make_float4(0.f, 0.f, 0.f, 0.f);
    int r = s0;
    for (; r + 8 <= s1; r += 8) {
        const float4 v0 = *reinterpret_cast<const float4*>(x + (size_t)(r + rs)     * IN_CH + cq);
        const float4 v1 = *reinterpret_cast<const float4*>(x + (size_t)(r + 4 + rs) * IN_CH + cq);
        a0.x += v0.x; a0.y += v0.y; a0.z += v0.z; a0.w += v0.w;
        a1.x += v1.x; a1.y += v1.y; a1.z += v1.z; a1.w += v1.w;
    }
    if (r + 4 <= s1) {
        const float4 v = *reinterpret_cast<const float4*>(x + (size_t)(r + rs) * IN_CH + cq);
        a0.x += v.x; a0.y += v.y; a0.z += v.z; a0.w += v.w;
        r += 4;
    }
    if (r + rs < s1) {
        const float4 v = *reinterpret_cast<const float4*>(x + (size_t)(r + rs) * IN_CH + cq);
        a1.x += v.x; a1.y += v.y; a1.z += v.z; a1.w += v.w;
    }

    float sx = a0.x + a1.x;
    float sy = a0.y + a1.y;
    float sz = a0.z + a1.z;
    float sw = a0.w + a1.w;

    // Butterfly over the 4 row streams: after this EVERY lane holds the full
    // segment sum for its channel quad [cq, cq+3].
    sx += __shfl_xor(sx, 16); sy += __shfl_xor(sy, 16);
    sz += __shfl_xor(sz, 16); sw += __shfl_xor(sw, 16);
    sx += __shfl_xor(sx, 32); sy += __shfl_xor(sy, 32);
    sz += __shfl_xor(sz, 32); sw += __shfl_xor(sw, 32);

    const float cnt = (float)(s1 - s0);
    const float m0 = sx / cnt;
    const float m1 = sy / cnt;
    const float m2 = sz / cnt;
    const float m3 = sw / cnt;

    // Epilogue: out[g][l], out[g][l+64]. Mean channel c lives in lane (c>>2),
    // component (c&3); compile-time-lane __shfl -> v_readlane broadcast.
    float o0 = bias[l];
    float o1 = bias[l + 64];
    #pragma unroll
    for (int c = 0; c < IN_CH; ++c) {
        float m;
        switch (c & 3) {
            case 0:  m = __shfl(m0, c >> 2); break;
            case 1:  m = __shfl(m1, c >> 2); break;
            case 2:  m = __shfl(m2, c >> 2); break;
            default: m = __shfl(m3, c >> 2); break;
        }
        o0 = fmaf(w_lds[c * 129 + l],      m, o0);
        o1 = fmaf(w_lds[c * 129 + l + 64], m, o1);
    }
    out[(size_t)g * OUT_CH + l]      = o0;
    out[(size_t)g * OUT_CH + l + 64] = o1;
}

extern "C" void kernel_launch(void* const* d_in, const int* in_sizes, int n_in,
                              void* d_out, int out_size, void* d_ws, size_t ws_size,
                              hipStream_t stream) {
    const float* x    = (const float*)d_in[0];
    const int*   ids  = (const int*)d_in[1];
    const float* W    = (const float*)d_in[2];
    const float* bias = (const float*)d_in[3];
    float* out = (float*)d_out;

    const int N = in_sizes[1];             // 2,000,000
    const int G = out_size / OUT_CH;       // 16384

    int* starts = (int*)d_ws;              // (G+1) ints

    {
        const int block = 256;
        seg_starts_kernel<<<(N + block - 1) / block, block, 0, stream>>>(
            ids, N, G, starts);
    }
    {
        const int blocks = (G + WPB - 1) / WPB;   // 2048
        pool_linear_kernel<<<blocks, BLOCK, 0, stream>>>(x, W, bias, starts, out, G);
    }
}

// Round 3
// 100.267 us; speedup vs baseline: 1.2755x; 1.1151x over previous
//
#include <hip/hip_runtime.h>
#include <hip/hip_bf16.h>

// Problem: segment-mean over N=2,000,000 sorted nodes -> G=16384 graphs, then linear.
// x: [N,64] f32, segment_ids: [N] int32 (sorted), weight: [128,64] f32, bias: [128] f32.
// out: [G,128] f32.  HBM-bound: ~520 MB read + 8 MB write -> ~84 us floor.
//
// Single fused kernel: each wave owns one graph, finds its row range itself via a
// windowed binary search on the sorted ids (no starts[] pass, no second launch).

#define IN_CH 64
#define OUT_CH 128
#define WPB 8               // waves (= graphs) per block
#define BLOCK (WPB * 64)    // 512 threads

typedef float f32x4 __attribute__((ext_vector_type(4)));

__global__ __launch_bounds__(BLOCK) void fused_pool_linear_kernel(
        const float* __restrict__ x, const int* __restrict__ ids,
        const float* __restrict__ W, const float* __restrict__ bias,
        float* __restrict__ out, int N, int G) {
    // W transposed: w_lds[c*129 + o] = W[o][c]; stride 129 -> conflict-free.
    __shared__ float w_lds[IN_CH * 129];

    const int t  = threadIdx.x;
    const int wv = t >> 6;        // wave in block 0..7
    const int l  = t & 63;        // lane
    const int g  = blockIdx.x * WPB + wv;

    // ---- Per-wave range search: lower_bound(ids, g) and lower_bound(ids, g+1).
    // Even lanes search target g, odd lanes g+1 (lanes >=2 are redundant copies,
    // so each gather touches only 2 distinct addresses). ids are ~uniform, so
    // lower_bound(tgt) ~= tgt*N/G; use a +-4096 window (>5 sigma), validated,
    // with full-range fallback -> correct for ANY sorted input.
    int s0 = 0, s1 = 0;
    if (g < G) {
        const int target = g + (l & 1);
        int lo = 0, hi = N;
        const int guess = (int)(((long long)target * (long long)N) / (long long)G);
        int wlo = guess - 4096; if (wlo < 0) wlo = 0;
        int whi = guess + 4096; if (whi > N) whi = N;
        const bool ok_lo = (wlo == 0) || (ids[wlo - 1] < target);
        const bool ok_hi = (whi == N) || (ids[whi] >= target);
        if (ok_lo && ok_hi) { lo = wlo; hi = whi; }
        while (lo < hi) {
            const int mid = (lo + hi) >> 1;
            if (ids[mid] < target) lo = mid + 1; else hi = mid;
        }
        s0 = __shfl(lo, 0);
        s1 = __shfl(lo, 1);
    }

    // ---- Stage W into LDS (after the search chains issue; independent loads).
    for (int i = t; i < OUT_CH * IN_CH; i += BLOCK) {
        const int o = i >> 6;     // 0..127
        const int c = i & 63;     // 0..63
        w_lds[c * 129 + o] = W[i];
    }
    __syncthreads();              // only barrier; all threads reach it

    if (g >= G) return;

    const int rs = l >> 4;              // row stream 0..3
    const int cq = (l & 15) << 2;       // channel quad base

    // ---- Stream the segment: 8 rows / iter, two 1 KiB wave-loads in flight.
    // Nontemporal: x is read-once (512 MB) - keep it out of L2/L3 so the ids
    // stay cached for later blocks' searches.
    float4 a0 = make_float4(0.f, 0.f, 0.f, 0.f);
    float4 a1 = make_float4(0.f, 0.f, 0.f, 0.f);
    int r = s0;
    for (; r + 8 <= s1; r += 8) {
        const f32x4 v0 = __builtin_nontemporal_load(
            reinterpret_cast<const f32x4*>(x + (size_t)(r + rs) * IN_CH + cq));
        const f32x4 v1 = __builtin_nontemporal_load(
            reinterpret_cast<const f32x4*>(x + (size_t)(r + 4 + rs) * IN_CH + cq));
        a0.x += v0.x; a0.y += v0.y; a0.z += v0.z; a0.w += v0.w;
        a1.x += v1.x; a1.y += v1.y; a1.z += v1.z; a1.w += v1.w;
    }
    if (r + 4 <= s1) {
        const f32x4 v = __builtin_nontemporal_load(
            reinterpret_cast<const f32x4*>(x + (size_t)(r + rs) * IN_CH + cq));
        a0.x += v.x; a0.y += v.y; a0.z += v.z; a0.w += v.w;
        r += 4;
    }
    if (r + rs < s1) {
        const f32x4 v = __builtin_nontemporal_load(
            reinterpret_cast<const f32x4*>(x + (size_t)(r + rs) * IN_CH + cq));
        a1.x += v.x; a1.y += v.y; a1.z += v.z; a1.w += v.w;
    }

    float sx = a0.x + a1.x;
    float sy = a0.y + a1.y;
    float sz = a0.z + a1.z;
    float sw = a0.w + a1.w;

    // Butterfly over the 4 row streams: every lane ends with the full segment
    // sum for its channel quad [cq, cq+3].
    sx += __shfl_xor(sx, 16); sy += __shfl_xor(sy, 16);
    sz += __shfl_xor(sz, 16); sw += __shfl_xor(sw, 16);
    sx += __shfl_xor(sx, 32); sy += __shfl_xor(sy, 32);
    sz += __shfl_xor(sz, 32); sw += __shfl_xor(sw, 32);

    const float cnt = (float)(s1 - s0);
    const float m0 = sx / cnt;
    const float m1 = sy / cnt;
    const float m2 = sz / cnt;
    const float m3 = sw / cnt;

    // ---- Epilogue: out[g][l], out[g][l+64]. Mean channel c lives in lane
    // (c>>2), component (c&3); compile-time-lane __shfl -> v_readlane.
    float o0 = bias[l];
    float o1 = bias[l + 64];
    #pragma unroll
    for (int c = 0; c < IN_CH; ++c) {
        float m;
        switch (c & 3) {
            case 0:  m = __shfl(m0, c >> 2); break;
            case 1:  m = __shfl(m1, c >> 2); break;
            case 2:  m = __shfl(m2, c >> 2); break;
            default: m = __shfl(m3, c >> 2); break;
        }
        o0 = fmaf(w_lds[c * 129 + l],      m, o0);
        o1 = fmaf(w_lds[c * 129 + l + 64], m, o1);
    }
    out[(size_t)g * OUT_CH + l]      = o0;
    out[(size_t)g * OUT_CH + l + 64] = o1;
}

extern "C" void kernel_launch(void* const* d_in, const int* in_sizes, int n_in,
                              void* d_out, int out_size, void* d_ws, size_t ws_size,
                              hipStream_t stream) {
    const float* x    = (const float*)d_in[0];
    const int*   ids  = (const int*)d_in[1];
    const float* W    = (const float*)d_in[2];
    const float* bias = (const float*)d_in[3];
    float* out = (float*)d_out;

    const int N = in_sizes[1];             // 2,000,000
    const int G = out_size / OUT_CH;       // 16384

    const int blocks = (G + WPB - 1) / WPB;   // 2048
    fused_pool_linear_kernel<<<blocks, BLOCK, 0, stream>>>(
        x, ids, W, bias, out, N, G);
}